// Round 6
// baseline (202.031 us; speedup 1.0000x reference)
//
#include <hip/hip_runtime.h>
#include <hip/hip_bf16.h>

typedef __hip_bfloat16 bf16;
typedef __attribute__((ext_vector_type(8))) short   bf16x8;  // 8 bf16 = 4 VGPRs
typedef __attribute__((ext_vector_type(4))) float   f32x4;

#define B_   4
#define S_   4096
#define D_   768
#define NH_  8
#define DK_  64
#define DV_  64
#define CH_  64              // chunk length
#define NCH_ (S_/CH_)        // 64 chunks
#define DECAY_ 0.95f
#define WSTR_  0.1f

__device__ __forceinline__ float b2f(bf16 v) { return __bfloat162float(v); }
__device__ __forceinline__ bf16  f2b(float v) { return __float2bfloat16(v); }

// async global -> LDS, 16 bytes per lane; lds base must be wave-uniform,
// HW writes lane i at lds + i*16.
__device__ __forceinline__ void gl2lds16(const bf16* g, bf16* lds) {
    __builtin_amdgcn_global_load_lds(
        (const __attribute__((address_space(1))) void*)g,
        (__attribute__((address_space(3))) void*)lds, 16, 0, 0);
}

__device__ __forceinline__ void cvt4(ushort4 u, float f[4]) {
    union { unsigned u; float f; } c;
    c.u = (unsigned)u.x << 16; f[0] = c.f;
    c.u = (unsigned)u.y << 16; f[1] = c.f;
    c.u = (unsigned)u.z << 16; f[2] = c.f;
    c.u = (unsigned)u.w << 16; f[3] = c.f;
}

// ---------------------------------------------------------------------------
// prep kernel (replaces cast_fused's x-cast): gate for batch-0 rows + the
// four weight-matrix casts. x fp32 -> bf16 cast is ELIMINATED: proj_fused
// now consumes x directly (reg-staged cvt). ~21MB traffic vs ~81MB before.
//  blocks [0,4096): gate rows;  blocks [4096,6144): weight casts.
// ---------------------------------------------------------------------------
__global__ __launch_bounds__(192) void prep(const float* __restrict__ x,
                                            const float* __restrict__ wg,
                                            float* __restrict__ wgt,
                                            const float* __restrict__ wq,
                                            const float* __restrict__ wk,
                                            const float* __restrict__ wv,
                                            const float* __restrict__ wo,
                                            bf16* __restrict__ dq, bf16* __restrict__ dk,
                                            bf16* __restrict__ dv, bf16* __restrict__ dob) {
    const int tid = threadIdx.x;
    if (blockIdx.x >= S_) {
        const int idx = blockIdx.x - S_;               // 0..2047
        const int which = idx >> 9, b = idx & 511;     // 512 blocks per matrix
        const float* src = which == 0 ? wq : which == 1 ? wk : which == 2 ? wv : wo;
        bf16*       dst = which == 0 ? dq : which == 1 ? dk : which == 2 ? dv : dob;
        const int i = (b * 192 + tid) * 4;
        const float4 v = *reinterpret_cast<const float4*>(src + i);
        union { bf16 b4[4]; ushort4 u; } t;
        t.b4[0] = f2b(v.x); t.b4[1] = f2b(v.y); t.b4[2] = f2b(v.z); t.b4[3] = f2b(v.w);
        *reinterpret_cast<ushort4*>(dst + i) = t.u;
        return;
    }
    const int s = blockIdx.x;                          // gate row (batch 0)
    const float4 v = *reinterpret_cast<const float4*>(x + (size_t)s * D_ + tid * 4);
    __shared__ float red[3 * 8];
    float p[8];
    const float* wgp = wg + tid * 4;
    #pragma unroll
    for (int h = 0; h < 8; h++) {
        const float4 wv4 = *reinterpret_cast<const float4*>(wgp + h * D_);
        p[h] = v.x * wv4.x + v.y * wv4.y + v.z * wv4.z + v.w * wv4.w;
    }
    #pragma unroll
    for (int h = 0; h < 8; h++)
        #pragma unroll
        for (int off = 32; off; off >>= 1) p[h] += __shfl_down(p[h], off);
    const int w = tid >> 6, lane = tid & 63;
    if (lane == 0) {
        #pragma unroll
        for (int h = 0; h < 8; h++) red[w * 8 + h] = p[h];
    }
    __syncthreads();
    if (tid < 8) {
        const float sum = red[tid] + red[8 + tid] + red[16 + tid];
        wgt[s * NH_ + tid] = WSTR_ / (1.f + expf(-sum));
    }
}

// ---------------------------------------------------------------------------
// proj GEMM body with fp32-A reg-staging: A = x (fp32), cvt to bf16 in-reg,
// ds_write into the SAME swizzled-source/linear-dest LDS layout gl2lds used.
// Pipeline (all waits have >= 1-iteration windows; exact vmcnt accounting):
//  entering iter it: As[cur]=A(it) (ds-written last iter), Bs=B(it) (gl2lds
//  last iter), a4[] regs = raw fp32 A(it+1) in flight.  Queue=[B(it)4,A(it+1)8]
//   1. vmcnt(8) -> B(it) done;  lgkmcnt(0);  barrier1
//   2. 16 ds_read frags; lgkmcnt(0); barrier2
//   3. vmcnt(0) -> A(it+1) raw arrived (full-iter window); cvt+ds_write
//      -> As[cur^1];  issue B(it+1) gl2lds (Bs free per barrier2);
//      issue A(it+2) raw loads
//   4. 32 MFMA (pure reg)
// ---------------------------------------------------------------------------
template<int NITER>
__device__ __forceinline__ void gemm_projA(bf16* As, bf16* Bs,
                                           const float* __restrict__ A,
                                           const bf16* __restrict__ Bm,
                                           bf16* __restrict__ C,
                                           int bm, int bn, int K, int N) {
    const int tid = threadIdx.x, lane = tid & 63, w = tid >> 6;
    const int quad = lane >> 4, l16 = lane & 15;
    const int wm = (w >> 1) * 64, wn = (w & 1) * 64;
    const int lrow = lane >> 3;                         // 0..7 within segment
    const int lcol = ((lane & 7) ^ lrow) * 8;           // XOR-swizzled source col

    f32x4 acc[4][4] = {};
    float4 a4[8];                                       // raw fp32 A tile regs

    auto ALOAD = [&](int it) {
        const int k0 = it * 64;
        #pragma unroll
        for (int c = 0; c < 4; c++) {
            const int row = (w * 4 + c) * 8 + lrow;
            const float* p = A + (size_t)(bm + row) * K + k0 + lcol;
            a4[2 * c]     = *reinterpret_cast<const float4*>(p);
            a4[2 * c + 1] = *reinterpret_cast<const float4*>(p + 4);
        }
    };
    auto AWRITE = [&](int buf) {
        bf16* Ad = As + buf * 8192;
        #pragma unroll
        for (int c = 0; c < 4; c++) {
            union { bf16 b8[8]; bf16x8 v; } t;
            t.b8[0] = f2b(a4[2*c].x);   t.b8[1] = f2b(a4[2*c].y);
            t.b8[2] = f2b(a4[2*c].z);   t.b8[3] = f2b(a4[2*c].w);
            t.b8[4] = f2b(a4[2*c+1].x); t.b8[5] = f2b(a4[2*c+1].y);
            t.b8[6] = f2b(a4[2*c+1].z); t.b8[7] = f2b(a4[2*c+1].w);
            *reinterpret_cast<bf16x8*>(&Ad[(w * 4 + c) * 512 + lane * 8]) = t.v;
        }
    };
    auto STAGE_B = [&](int it) {
        const int k0 = it * 64;
        #pragma unroll
        for (int c = 0; c < 4; c++) {
            const int seg = w * 4 + c;
            const int row = seg * 8 + lrow;
            gl2lds16(Bm + (size_t)(bn + row) * K + k0 + lcol, &Bs[seg * 512]);
        }
    };

    // prologue: A(0) via regs, then B(0) + A(1) in flight
    ALOAD(0);
    asm volatile("s_waitcnt vmcnt(0)" ::: "memory");
    AWRITE(0);
    STAGE_B(0);                                         // queue [B0:4]
    ALOAD(1);                                           // queue [B0:4, A1:8]

    for (int it = 0; it < NITER; ++it) {
        const int cur = it & 1;
        if (it + 1 < NITER)
            asm volatile("s_waitcnt vmcnt(8)" ::: "memory");  // B(it) done
        else
            asm volatile("s_waitcnt vmcnt(0)" ::: "memory");
        asm volatile("s_waitcnt lgkmcnt(0)" ::: "memory");    // A writes drained
        __builtin_amdgcn_s_barrier();                   // barrier1
        asm volatile("" ::: "memory");

        const bf16* Ar = As + cur * 8192;
        bf16x8 af[2][4], bfr[2][4];
        #pragma unroll
        for (int kh = 0; kh < 2; kh++)
            #pragma unroll
            for (int t = 0; t < 4; t++) {
                const int cb = ((kh * 4 + quad) ^ (l16 & 7)) * 8;
                af[kh][t]  = *reinterpret_cast<const bf16x8*>(&Ar[(wm + t * 16 + l16) * 64 + cb]);
                bfr[kh][t] = *reinterpret_cast<const bf16x8*>(&Bs[(wn + t * 16 + l16) * 64 + cb]);
            }
        asm volatile("s_waitcnt lgkmcnt(0)" ::: "memory");    // frags in regs
        __builtin_amdgcn_s_barrier();                   // barrier2: LDS free
        asm volatile("" ::: "memory");

        if (it + 1 < NITER) {
            asm volatile("s_waitcnt vmcnt(0)" ::: "memory");  // A(it+1) raw in
            AWRITE(cur ^ 1);                            // As[cur^1] <- A(it+1)
            STAGE_B(it + 1);                            // queue [B:4]
            if (it + 2 < NITER) ALOAD(it + 2);          // queue [B:4, A:8]
        }

        #pragma unroll
        for (int kh = 0; kh < 2; kh++)
            #pragma unroll
            for (int mt = 0; mt < 4; mt++)
                #pragma unroll
                for (int nt = 0; nt < 4; nt++)
                    acc[mt][nt] = __builtin_amdgcn_mfma_f32_16x16x32_bf16(
                        af[kh][mt], bfr[kh][nt], acc[mt][nt], 0, 0, 0);
    }

    #pragma unroll
    for (int mt = 0; mt < 4; mt++)
        #pragma unroll
        for (int nt = 0; nt < 4; nt++)
            #pragma unroll
            for (int r = 0; r < 4; r++) {
                const int m = bm + wm + mt * 16 + quad * 4 + r;
                const int n = bn + wn + nt * 16 + l16;
                C[(size_t)m * N + n] = f2b(acc[mt][nt][r]);
            }
}

// ---------------------------------------------------------------------------
// Shared MFMA GEMM body v4 (unchanged, proven): A-dbuf gl2lds + B single.
// ---------------------------------------------------------------------------
template<typename TC, int ADDX, int NITER>
__device__ __forceinline__ void gemm_body(bf16* As, bf16* Bs,
                                          const bf16* __restrict__ A,
                                          const bf16* __restrict__ Bm,
                                          const float* __restrict__ X,
                                          TC* __restrict__ C,
                                          int bm, int bn, int K, int N) {
    const int tid = threadIdx.x, lane = tid & 63, w = tid >> 6;
    const int quad = lane >> 4, l16 = lane & 15;
    const int wm = (w >> 1) * 64, wn = (w & 1) * 64;
    const int lrow = lane >> 3;                         // 0..7 within segment
    const int lcol = ((lane & 7) ^ lrow) * 8;           // XOR-swizzled source col

    f32x4 acc[4][4] = {};

    auto STAGE_A = [&](int it, int buf) {
        const int k0 = it * 64;
        bf16* Ad = As + buf * 8192;
        #pragma unroll
        for (int c = 0; c < 4; c++) {
            const int seg = w * 4 + c;                  // 0..15, 8 rows each
            const int row = seg * 8 + lrow;
            gl2lds16(A + (size_t)(bm + row) * K + k0 + lcol, &Ad[seg * 512]);
        }
    };
    auto STAGE_B = [&](int it) {
        const int k0 = it * 64;
        #pragma unroll
        for (int c = 0; c < 4; c++) {
            const int seg = w * 4 + c;
            const int row = seg * 8 + lrow;
            gl2lds16(Bm + (size_t)(bn + row) * K + k0 + lcol, &Bs[seg * 512]);
        }
    };

    STAGE_A(0, 0);          // oldest in queue
    STAGE_B(0);

    for (int it = 0; it < NITER; ++it) {
        const int cur = it & 1;
        if (it + 1 < NITER) {
            STAGE_A(it + 1, cur ^ 1);                   // full-iter window
            asm volatile("s_waitcnt vmcnt(4)" ::: "memory");  // A(it)+B(it) in
        } else {
            asm volatile("s_waitcnt vmcnt(0)" ::: "memory");
        }
        __builtin_amdgcn_s_barrier();                   // barrier1: tiles visible
        asm volatile("" ::: "memory");

        const bf16* Ar = As + cur * 8192;
        bf16x8 af[2][4], bfr[2][4];
        #pragma unroll
        for (int kh = 0; kh < 2; kh++)
            #pragma unroll
            for (int t = 0; t < 4; t++) {
                const int cb = ((kh * 4 + quad) ^ (l16 & 7)) * 8;
                af[kh][t]  = *reinterpret_cast<const bf16x8*>(&Ar[(wm + t * 16 + l16) * 64 + cb]);
                bfr[kh][t] = *reinterpret_cast<const bf16x8*>(&Bs[(wn + t * 16 + l16) * 64 + cb]);
            }
        asm volatile("s_waitcnt lgkmcnt(0)" ::: "memory");    // frags in regs
        __builtin_amdgcn_s_barrier();                   // barrier2: LDS free
        if (it + 1 < NITER) STAGE_B(it + 1);            // latency hides in MFMAs

        #pragma unroll
        for (int kh = 0; kh < 2; kh++)
            #pragma unroll
            for (int mt = 0; mt < 4; mt++)
                #pragma unroll
                for (int nt = 0; nt < 4; nt++)
                    acc[mt][nt] = __builtin_amdgcn_mfma_f32_16x16x32_bf16(
                        af[kh][mt], bfr[kh][nt], acc[mt][nt], 0, 0, 0);
    }

    #pragma unroll
    for (int mt = 0; mt < 4; mt++)
        #pragma unroll
        for (int nt = 0; nt < 4; nt++)
            #pragma unroll
            for (int r = 0; r < 4; r++) {
                const int m = bm + wm + mt * 16 + quad * 4 + r;
                const int n = bn + wn + nt * 16 + l16;
                float v = acc[mt][nt][r];
                if (ADDX) v += X[(size_t)m * N + n];
                if (sizeof(TC) == 2) *(bf16*)&C[(size_t)m * N + n] = f2b(v);
                else                 *(float*)&C[(size_t)m * N + n] = v;
            }
}

// ---------------------------------------------------------------------------
// Fused q/k/v projection: 768 blocks, K=768, N=512; A = x fp32 (reg-staged).
// ---------------------------------------------------------------------------
__global__ __launch_bounds__(256, 3) void proj_fused(const float* __restrict__ x,
                                                  const bf16* __restrict__ wqb,
                                                  const bf16* __restrict__ wkb,
                                                  const bf16* __restrict__ wvb,
                                                  bf16* __restrict__ qbuf,
                                                  bf16* __restrict__ k0buf,
                                                  bf16* __restrict__ v0buf) {
    __shared__ bf16 As[2 * 128 * 64];   // A double-buffer (32KB)
    __shared__ bf16 Bs[128 * 64];       // B single (16KB) -> 48KB, 3 blocks/CU
    const int id = blockIdx.x;
    const int xcd = id & 7;
    int j = id >> 3;                                    // 0..95
    const bf16* Bm; bf16* C; int bm, bn;
    if (j < 64) {
        bm = (xcd + ((j >> 2) << 3)) * 128;             // q strip
        bn = (j & 3) * 128;
        Bm = wqb; C = qbuf;
    } else {
        j -= 64;
        bm = (xcd + ((j >> 3) << 3)) * 128;             // kv strip (rows < 4096)
        const int b8 = j & 7;
        bn = (b8 & 3) * 128;
        Bm = (b8 < 4) ? wkb : wvb;
        C  = (b8 < 4) ? k0buf : v0buf;
    }
    gemm_projA<12>(As, Bs, x, Bm, C, bm, bn, D_, 512);
}

// ---------------------------------------------------------------------------
// Out-projection: out = x + retr @ wo^T.  grid (6,128), K=512, N=768.
// ---------------------------------------------------------------------------
__global__ __launch_bounds__(256, 3) void gemm_out(const bf16* __restrict__ retr,
                                                const bf16* __restrict__ wob,
                                                const float* __restrict__ x,
                                                float* __restrict__ out) {
    __shared__ bf16 As[2 * 128 * 64];
    __shared__ bf16 Bs[128 * 64];
    // XCD swizzle: blocks sharing an A-strip (by) land on one XCD.
    const int gx = gridDim.x, gy = gridDim.y;
    const int L = blockIdx.y * gx + blockIdx.x;
    const int rpx = gy >> 3;
    const int xcd = L & 7;
    const int i   = L >> 3;
    const int by = xcd * rpx + i / gx;
    const int bx = i % gx;
    gemm_body<float, 1, 8>(As, Bs, retr, wob, x, out, by * 128, bx * 128, 512, D_);
}

// ---------------------------------------------------------------------------
// lsumsT[n,h][v*64+k] = sum_{i<CH} 0.95^(CH-1-i) * w_i * v_i[v] * k_i[k]
// ---------------------------------------------------------------------------
__global__ __launch_bounds__(256) void chunk_sums(const bf16* __restrict__ k0,
                                                  const bf16* __restrict__ v0,
                                                  const float* __restrict__ wgt,
                                                  bf16* __restrict__ lsumsT) {
    const int n = blockIdx.x, h = blockIdx.y;
    __shared__ float ks[CH_][65];
    __shared__ float vs[CH_][64];
    __shared__ float cw[CH_];
    const int tid = threadIdx.x;
    for (int e = tid; e < CH_ * 64; e += 256) {
        const int r = e >> 6, c = e & 63;
        const int t = n * CH_ + r;
        ks[r][c] = b2f(k0[(size_t)t * (NH_ * DK_) + h * DK_ + c]);
        vs[r][c] = b2f(v0[(size_t)t * (NH_ * DV_) + h * DV_ + c]);
    }
    if (tid < CH_) {
        const int t = n * CH_ + tid;
        cw[tid] = powf(DECAY_, (float)(CH_ - 1 - tid)) * wgt[t * NH_ + h];
    }
    __syncthreads();
    const int j = tid & 63, ig = tid >> 6;   // j = k-dim, rows = v-dim
    float acc[16] = {};
    for (int idx = 0; idx < CH_; idx++) {
        const float ck = cw[idx] * ks[idx][j];
        #pragma unroll
        for (int r = 0; r < 16; r++) acc[r] += vs[idx][ig * 16 + r] * ck;
    }
    bf16* outp = lsumsT + ((size_t)(n * NH_ + h)) * (DK_ * DV_);
    #pragma unroll
    for (int r = 0; r < 16; r++) outp[(ig * 16 + r) * 64 + j] = f2b(acc[r]);
}

// ---------------------------------------------------------------------------
// chunk_output, batch-merged (R4 proven version, unchanged).
// ---------------------------------------------------------------------------
__global__ __launch_bounds__(256) void chunk_output(const bf16* __restrict__ q,
                                                    const bf16* __restrict__ k0,
                                                    const bf16* __restrict__ v0,
                                                    const float* __restrict__ wgt,
                                                    const bf16* __restrict__ lsumsT,
                                                    bf16* __restrict__ retr) {
    const int n = blockIdx.x, h = blockIdx.y;
    __shared__ bf16 QsAm[4][64 * 64];   // per-batch Q (sw64), then Am (sw64)
    __shared__ bf16 Ks[64 * 64];        // sw64
    __shared__ bf16 FWT[64 * 64];       // sw64
    __shared__ bf16 VT[64 * 72];        // stride 72
    __shared__ float dpow[64], winv[64];
    const int tid = threadIdx.x, lane = tid & 63, w = tid >> 6;  // w = batch
    const int quad = lane >> 4, l16 = lane & 15;
    const int t0 = n * CH_;
    const int lrow = lane >> 3;
    const int lcol = ((lane & 7) ^ lrow) * 8;           // XOR-swizzled source col

    #pragma unroll
    for (int seg = 0; seg < 8; seg++) {
        const int row = seg * 8 + lrow;
        gl2lds16(q + ((size_t)(w * S_ + t0 + row)) * 512 + h * 64 + lcol, &QsAm[w][seg * 512]);
    }
    #pragma unroll
    for (int c = 0; c < 2; c++) {
        const int seg = w * 2 + c;
        const int row = seg * 8 + lrow;
        gl2lds16(k0 + ((size_t)(t0 + row)) * 512 + h * 64 + lcol, &Ks[seg * 512]);
    }
    {
        float fwacc[16] = {};
        const float dcp[4] = { 1.0f, 0.0375241f, 1.40806e-3f, 5.28365e-5f };
        #pragma unroll
        for (int jj = 1; jj <= 4; jj++) {
            const int nm = n - jj;
            if (nm < 0) break;
            const ushort* Lp = (const ushort*)(lsumsT + ((size_t)(nm * NH_ + h)) * 4096) + tid * 16;
            #pragma unroll
            for (int u = 0; u < 4; u++) {
                float f[4];
                cvt4(reinterpret_cast<const ushort4*>(Lp)[u], f);
                #pragma unroll
                for (int e = 0; e < 4; e++) fwacc[u * 4 + e] += dcp[jj - 1] * f[e];
            }
        }
        const int frow = tid >> 2;                       // FWT row (v-dim)
        #pragma unroll
        for (int half = 0; half < 2; half++) {
            const int cb = (tid & 3) * 2 + half;         // logical colblock
            union { bf16 b8v[8]; bf16x8 v; } t;
            #pragma unroll
            for (int e = 0; e < 8; e++) t.b8v[e] = f2b(fwacc[half * 8 + e]);
            *reinterpret_cast<bf16x8*>(&FWT[frow * 64 + (cb ^ (frow & 7)) * 8]) = t.v;
        }
    }
    {
        ushort4 vreg[4];
        const int jb = (tid & 15) * 4;   // 4 consecutive v-cols
        const int sb = tid >> 4;         // s = sb + 16*it
        #pragma unroll
        for (int it = 0; it < 4; it++)
            vreg[it] = *reinterpret_cast<const ushort4*>(
                v0 + ((size_t)(t0 + sb + it * 16)) * 512 + h * 64 + jb);
        ushort* VTu = reinterpret_cast<ushort*>(VT);
        #pragma unroll
        for (int it = 0; it < 4; it++) {
            const int s = sb + it * 16;
            VTu[(jb + 0) * 72 + s] = vreg[it].x;
            VTu[(jb + 1) * 72 + s] = vreg[it].y;
            VTu[(jb + 2) * 72 + s] = vreg[it].z;
            VTu[(jb + 3) * 72 + s] = vreg[it].w;
        }
    }
    if (tid < 64) {
        dpow[tid] = powf(DECAY_, (float)tid);
        winv[tid] = wgt[(t0 + tid) * NH_ + h] * powf(DECAY_, -(float)(tid + 1));
    }
    __syncthreads();   // only barrier: drains gl2lds, covers FWT/VT/dpow/winv

    const int cb0 = ((quad) ^ (l16 & 7)) * 8;
    const int cb1 = ((4 + quad) ^ (l16 & 7)) * 8;
    bf16* Qw = &QsAm[w][0];

    bf16x8 af[4][2];
    #pragma unroll
    for (int mt = 0; mt < 4; mt++) {
        af[mt][0] = *reinterpret_cast<const bf16x8*>(&Qw[(mt * 16 + l16) * 64 + cb0]);
        af[mt][1] = *reinterpret_cast<const bf16x8*>(&Qw[(mt * 16 + l16) * 64 + cb1]);
    }
    f32x4 acc[4][4] = {};
    #pragma unroll
    for (int kh = 0; kh < 2; kh++) {
        bf16x8 bk[4];
        #pragma unroll
        for (int nt = 0; nt < 4; nt++)
            bk[nt] = *reinterpret_cast<const bf16x8*>(
                &Ks[(nt * 16 + l16) * 64 + (kh ? cb1 : cb0)]);
        #pragma unroll
        for (int mt = 0; mt < 4; mt++)
            #pragma unroll
            for (int nt = 0; nt < 4; nt++)
                acc[mt][nt] = __builtin_amdgcn_mfma_f32_16x16x32_bf16(
                    af[mt][kh], bk[nt], acc[mt][nt], 0, 0, 0);
    }
    const float pmt[4] = { 1.0f, 0.4401266694f, 0.1937114891f, 0.0852578070f };
    const f32x4 dpb = *reinterpret_cast<const f32x4*>(&dpow[quad * 4]);
    float winv_l[4];
    #pragma unroll
    for (int nt = 0; nt < 4; nt++) winv_l[nt] = winv[nt * 16 + l16];
    #pragma unroll
    for (int mt = 0; mt < 4; mt++)
        #pragma unroll
        for (int nt = 0; nt < 4; nt++)
            #pragma unroll
            for (int r = 0; r < 4; r++) {
                const int tt = mt * 16 + quad * 4 + r;
                const int s = nt * 16 + l16;
                const float v = (s < tt) ? acc[mt][nt][r] * (dpb[r] * pmt[mt]) * winv_l[nt] : 0.f;
                Qw[tt * 64 + (((s >> 3) ^ (tt & 7)) << 3) + (s & 7)] = f2b(v);
            }
    f32x4 o[4][4] = {};
    #pragma unroll
    for (int kh = 0; kh < 2; kh++) {
        bf16x8 ff[4];
        #pragma unroll
        for (int nt = 0; nt < 4; nt++)
            ff[nt] = *reinterpret_cast<const bf16x8*>(
                &FWT[(nt * 16 + l16) * 64 + (kh ? cb1 : cb0)]);
        #pragma unroll
        for (int mt = 0; mt < 4; mt++)
            #pragma unroll
            for (int nt = 0; nt < 4; nt++)
                o[mt][nt] = __builtin_amdgcn_mfma_f32_16x16x32_bf16(
                    af[mt][kh], ff[nt], o[mt][nt], 0, 0, 0);
    }
    #pragma unroll
    for (int mt = 0; mt < 4; mt++)
        #pragma unroll
        for (int nt = 0; nt < 4; nt++)
            #pragma unroll
            for (int r = 0; r < 4; r++) o[mt][nt][r] *= dpb[r] * pmt[mt];
    #pragma unroll
    for (int kh = 0; kh < 2; kh++) {
        bf16x8 am[4], vf[4];
        #pragma unroll
        for (int mt = 0; mt < 4; mt++)
            am[mt] = *reinterpret_cast<const bf16x8*>(
                &Qw[(mt * 16 + l16) * 64 + (kh ? cb1 : cb0)]);
        #pragma unroll
        for (int nt = 0; nt < 4; nt++)
            vf[nt] = *reinterpret_cast<const bf16x8*>(
                &VT[(nt * 16 + l16) * 72 + kh * 32 + quad * 8]);
        #pragma unroll
        for (int mt = 0; mt < 4; mt++)
            #pragma unroll
            for (int nt = 0; nt < 4; nt++)
                o[mt][nt] = __builtin_amdgcn_mfma_f32_16x16x32_bf16(
                    am[mt], vf[nt], o[mt][nt], 0, 0, 0);
    }
    #pragma unroll
    for (int mt = 0; mt < 4; mt++)
        #pragma unroll
        for (int nt = 0; nt < 4; nt++)
            #pragma unroll
            for (int r = 0; r < 4; r++) {
                const int tt = mt * 16 + quad * 4 + r;
                retr[((size_t)(w * S_ + t0 + tt)) * 512 + h * 64 + nt * 16 + l16] =
                    f2b(o[mt][nt][r]);
            }
}

// ---------------------------------------------------------------------------
extern "C" void kernel_launch(void* const* d_in, const int* in_sizes, int n_in,
                              void* d_out, int out_size, void* d_ws, size_t ws_size,
                              hipStream_t stream) {
    const float* x  = (const float*)d_in[0];
    const float* wk = (const float*)d_in[1];
    const float* wv = (const float*)d_in[2];
    const float* wq = (const float*)d_in[3];
    const float* wg = (const float*)d_in[4];
    const float* wo = (const float*)d_in[5];
    float* out = (float*)d_out;

    const size_t MB1 = 1ull << 20;
    char* w = (char*)d_ws;
    bf16*  qbuf    = (bf16*)(w);                          // 16 MB
    bf16*  k0buf   = (bf16*)(w + 16 * MB1);               // 4 MB
    bf16*  v0buf   = (bf16*)(w + 20 * MB1);               // 4 MB
    float* wgt     = (float*)(w + 24 * MB1);              // 128 KB
    bf16*  wqb     = (bf16*)(w + 24 * MB1 + (128ull<<10));
    bf16*  wkb     = (bf16*)(w + 24 * MB1 + (128ull<<10) + 1*786432);
    bf16*  wvb     = (bf16*)(w + 24 * MB1 + (128ull<<10) + 2*786432);
    bf16*  wob     = (bf16*)(w + 24 * MB1 + (128ull<<10) + 3*786432);
    bf16*  lsumsT  = (bf16*)(w + 28 * MB1);               // 4 MB
    bf16*  retr    = (bf16*)(w + 32 * MB1);               // 16 MB

    const int MB = B_ * S_;  // 16384

    // gate + weight casts only (x cast eliminated; proj reads x fp32)
    prep<<<S_ + 2048, 192, 0, stream>>>(x, wg, wgt, wq, wk, wv, wo,
                                        wqb, wkb, wvb, wob);

    // fused q/k/v projections from fp32 x (reg-staged A)
    proj_fused<<<768, 256, 0, stream>>>(x, wqb, wkb, wvb, qbuf, k0buf, v0buf);

    // chunked scan (state combine fused into chunk_output, batch-merged)
    chunk_sums<<<dim3(NCH_, NH_), 256, 0, stream>>>(k0buf, v0buf, wgt, lsumsT);
    chunk_output<<<dim3(NCH_, NH_), 256, 0, stream>>>(qbuf, k0buf, v0buf, wgt, lsumsT, retr);

    // out = x + retrieved @ w_out^T
    gemm_out<<<dim3(D_ / 128, MB / 128), 256, 0, stream>>>(retr, wob, x, out);
}

// Round 7
// 184.925 us; speedup vs baseline: 1.0925x; 1.0925x over previous
//
#include <hip/hip_runtime.h>
#include <hip/hip_bf16.h>

typedef __hip_bfloat16 bf16;
typedef __attribute__((ext_vector_type(8))) short   bf16x8;  // 8 bf16 = 4 VGPRs
typedef __attribute__((ext_vector_type(4))) float   f32x4;

#define B_   4
#define S_   4096
#define D_   768
#define NH_  8
#define DK_  64
#define DV_  64
#define CH_  64              // chunk length
#define NCH_ (S_/CH_)        // 64 chunks
#define DECAY_ 0.95f
#define WSTR_  0.1f

__device__ __forceinline__ float b2f(bf16 v) { return __bfloat162float(v); }
__device__ __forceinline__ bf16  f2b(float v) { return __float2bfloat16(v); }

// async global -> LDS, 16 bytes per lane; lds base must be wave-uniform,
// HW writes lane i at lds + i*16.
__device__ __forceinline__ void gl2lds16(const bf16* g, bf16* lds) {
    __builtin_amdgcn_global_load_lds(
        (const __attribute__((address_space(1))) void*)g,
        (__attribute__((address_space(3))) void*)lds, 16, 0, 0);
}

__device__ __forceinline__ void cvt4(ushort4 u, float f[4]) {
    union { unsigned u; float f; } c;
    c.u = (unsigned)u.x << 16; f[0] = c.f;
    c.u = (unsigned)u.y << 16; f[1] = c.f;
    c.u = (unsigned)u.z << 16; f[2] = c.f;
    c.u = (unsigned)u.w << 16; f[3] = c.f;
}

// ---------------------------------------------------------------------------
// Fused cast kernel, 192 threads (R4 proven):
//  blocks [0, 16384): x row cast fp32->bf16; rows < 4096 also compute gate.
//  blocks [16384, 18432): the four 512x768 weight matrices cast (512 blk each).
// ---------------------------------------------------------------------------
__global__ __launch_bounds__(192) void cast_fused(const float* __restrict__ x,
                                                  bf16* __restrict__ xb,
                                                  const float* __restrict__ wg,
                                                  float* __restrict__ wgt,
                                                  const float* __restrict__ wq,
                                                  const float* __restrict__ wk,
                                                  const float* __restrict__ wv,
                                                  const float* __restrict__ wo,
                                                  bf16* __restrict__ dq, bf16* __restrict__ dk,
                                                  bf16* __restrict__ dv, bf16* __restrict__ dob) {
    const int tid = threadIdx.x;
    if (blockIdx.x >= (B_ * S_)) {
        const int idx = blockIdx.x - B_ * S_;          // 0..2047
        const int which = idx >> 9, b = idx & 511;     // 512 blocks per matrix
        const float* src = which == 0 ? wq : which == 1 ? wk : which == 2 ? wv : wo;
        bf16*       dst = which == 0 ? dq : which == 1 ? dk : which == 2 ? dv : dob;
        const int i = (b * 192 + tid) * 4;
        const float4 v = *reinterpret_cast<const float4*>(src + i);
        union { bf16 b4[4]; ushort4 u; } t;
        t.b4[0] = f2b(v.x); t.b4[1] = f2b(v.y); t.b4[2] = f2b(v.z); t.b4[3] = f2b(v.w);
        *reinterpret_cast<ushort4*>(dst + i) = t.u;
        return;
    }
    const int s = blockIdx.x;
    const float4 v = *reinterpret_cast<const float4*>(x + (size_t)s * D_ + tid * 4);
    union { bf16 b4[4]; ushort4 u; } t;
    t.b4[0] = f2b(v.x); t.b4[1] = f2b(v.y); t.b4[2] = f2b(v.z); t.b4[3] = f2b(v.w);
    *reinterpret_cast<ushort4*>(xb + (size_t)s * D_ + tid * 4) = t.u;

    if (s < S_) {   // batch 0 only
        __shared__ float red[3 * 8];
        float p[8];
        const float* wgp = wg + tid * 4;
        #pragma unroll
        for (int h = 0; h < 8; h++) {
            const float4 wv4 = *reinterpret_cast<const float4*>(wgp + h * D_);
            p[h] = v.x * wv4.x + v.y * wv4.y + v.z * wv4.z + v.w * wv4.w;
        }
        #pragma unroll
        for (int h = 0; h < 8; h++)
            #pragma unroll
            for (int off = 32; off; off >>= 1) p[h] += __shfl_down(p[h], off);
        const int w = tid >> 6, lane = tid & 63;
        if (lane == 0) {
            #pragma unroll
            for (int h = 0; h < 8; h++) red[w * 8 + h] = p[h];
        }
        __syncthreads();
        if (tid < 8) {
            const float sum = red[tid] + red[8 + tid] + red[16 + tid];
            wgt[s * NH_ + tid] = WSTR_ / (1.f + expf(-sum));
        }
    }
}

// ---------------------------------------------------------------------------
// Shared MFMA GEMM body v4 (R4 proven): A-dbuf gl2lds (32KB) + B single (16KB)
// = 48KB -> 3 blocks/CU. PIN (R3/R6): all staging must be global_load_lds;
// register round-trips lose even with full-iteration wait windows.
// ---------------------------------------------------------------------------
template<typename TC, int ADDX, int NITER>
__device__ __forceinline__ void gemm_body(bf16* As, bf16* Bs,
                                          const bf16* __restrict__ A,
                                          const bf16* __restrict__ Bm,
                                          const float* __restrict__ X,
                                          TC* __restrict__ C,
                                          int bm, int bn, int K, int N) {
    const int tid = threadIdx.x, lane = tid & 63, w = tid >> 6;
    const int quad = lane >> 4, l16 = lane & 15;
    const int wm = (w >> 1) * 64, wn = (w & 1) * 64;
    const int lrow = lane >> 3;                         // 0..7 within segment
    const int lcol = ((lane & 7) ^ lrow) * 8;           // XOR-swizzled source col

    f32x4 acc[4][4] = {};

    auto STAGE_A = [&](int it, int buf) {
        const int k0 = it * 64;
        bf16* Ad = As + buf * 8192;
        #pragma unroll
        for (int c = 0; c < 4; c++) {
            const int seg = w * 4 + c;                  // 0..15, 8 rows each
            const int row = seg * 8 + lrow;
            gl2lds16(A + (size_t)(bm + row) * K + k0 + lcol, &Ad[seg * 512]);
        }
    };
    auto STAGE_B = [&](int it) {
        const int k0 = it * 64;
        #pragma unroll
        for (int c = 0; c < 4; c++) {
            const int seg = w * 4 + c;
            const int row = seg * 8 + lrow;
            gl2lds16(Bm + (size_t)(bn + row) * K + k0 + lcol, &Bs[seg * 512]);
        }
    };

    STAGE_A(0, 0);          // oldest in queue
    STAGE_B(0);

    for (int it = 0; it < NITER; ++it) {
        const int cur = it & 1;
        if (it + 1 < NITER) {
            STAGE_A(it + 1, cur ^ 1);                   // full-iter window
            asm volatile("s_waitcnt vmcnt(4)" ::: "memory");  // A(it)+B(it) in
        } else {
            asm volatile("s_waitcnt vmcnt(0)" ::: "memory");
        }
        __builtin_amdgcn_s_barrier();                   // barrier1: tiles visible
        asm volatile("" ::: "memory");

        const bf16* Ar = As + cur * 8192;
        bf16x8 af[2][4], bfr[2][4];
        #pragma unroll
        for (int kh = 0; kh < 2; kh++)
            #pragma unroll
            for (int t = 0; t < 4; t++) {
                const int cb = ((kh * 4 + quad) ^ (l16 & 7)) * 8;
                af[kh][t]  = *reinterpret_cast<const bf16x8*>(&Ar[(wm + t * 16 + l16) * 64 + cb]);
                bfr[kh][t] = *reinterpret_cast<const bf16x8*>(&Bs[(wn + t * 16 + l16) * 64 + cb]);
            }
        asm volatile("s_waitcnt lgkmcnt(0)" ::: "memory");    // frags in regs
        __builtin_amdgcn_s_barrier();                   // barrier2: LDS free
        if (it + 1 < NITER) STAGE_B(it + 1);            // latency hides in MFMAs

        #pragma unroll
        for (int kh = 0; kh < 2; kh++)
            #pragma unroll
            for (int mt = 0; mt < 4; mt++)
                #pragma unroll
                for (int nt = 0; nt < 4; nt++)
                    acc[mt][nt] = __builtin_amdgcn_mfma_f32_16x16x32_bf16(
                        af[kh][mt], bfr[kh][nt], acc[mt][nt], 0, 0, 0);
    }

    #pragma unroll
    for (int mt = 0; mt < 4; mt++)
        #pragma unroll
        for (int nt = 0; nt < 4; nt++)
            #pragma unroll
            for (int r = 0; r < 4; r++) {
                const int m = bm + wm + mt * 16 + quad * 4 + r;
                const int n = bn + wn + nt * 16 + l16;
                float v = acc[mt][nt][r];
                if (ADDX) v += X[(size_t)m * N + n];
                if (sizeof(TC) == 2) *(bf16*)&C[(size_t)m * N + n] = f2b(v);
                else                 *(float*)&C[(size_t)m * N + n] = v;
            }
}

// ---------------------------------------------------------------------------
// Fused q/k/v projection: 768 blocks, K=768, N=512 for all.
// ---------------------------------------------------------------------------
__global__ __launch_bounds__(256, 3) void proj_fused(const bf16* __restrict__ xb,
                                                  const bf16* __restrict__ wqb,
                                                  const bf16* __restrict__ wkb,
                                                  const bf16* __restrict__ wvb,
                                                  bf16* __restrict__ qbuf,
                                                  bf16* __restrict__ k0buf,
                                                  bf16* __restrict__ v0buf) {
    __shared__ bf16 As[2 * 128 * 64];   // A double-buffer (32KB)
    __shared__ bf16 Bs[128 * 64];       // B single (16KB) -> 48KB, 3 blocks/CU
    const int id = blockIdx.x;
    const int xcd = id & 7;
    int j = id >> 3;                                    // 0..95
    const bf16* Bm; bf16* C; int bm, bn;
    if (j < 64) {
        bm = (xcd + ((j >> 2) << 3)) * 128;             // q strip
        bn = (j & 3) * 128;
        Bm = wqb; C = qbuf;
    } else {
        j -= 64;
        bm = (xcd + ((j >> 3) << 3)) * 128;             // kv strip (rows < 4096)
        const int b8 = j & 7;
        bn = (b8 & 3) * 128;
        Bm = (b8 < 4) ? wkb : wvb;
        C  = (b8 < 4) ? k0buf : v0buf;
    }
    gemm_body<bf16, 0, 12>(As, Bs, xb, Bm, nullptr, C, bm, bn, D_, 512);
}

// ---------------------------------------------------------------------------
// Out-projection: out = x + retr @ wo^T.  grid (6,128), K=512, N=768.
// ---------------------------------------------------------------------------
__global__ __launch_bounds__(256, 3) void gemm_out(const bf16* __restrict__ retr,
                                                const bf16* __restrict__ wob,
                                                const float* __restrict__ x,
                                                float* __restrict__ out) {
    __shared__ bf16 As[2 * 128 * 64];
    __shared__ bf16 Bs[128 * 64];
    // XCD swizzle: blocks sharing an A-strip (by) land on one XCD.
    const int gx = gridDim.x, gy = gridDim.y;
    const int L = blockIdx.y * gx + blockIdx.x;
    const int rpx = gy >> 3;
    const int xcd = L & 7;
    const int i   = L >> 3;
    const int by = xcd * rpx + i / gx;
    const int bx = i % gx;
    gemm_body<float, 1, 8>(As, Bs, retr, wob, x, out, by * 128, bx * 128, 512, D_);
}

// ---------------------------------------------------------------------------
// lsumsT[n,h][v*64+k] = sum_{i<CH} 0.95^(CH-1-i) * w_i * v_i[v] * k_i[k]
// ---------------------------------------------------------------------------
__global__ __launch_bounds__(256) void chunk_sums(const bf16* __restrict__ k0,
                                                  const bf16* __restrict__ v0,
                                                  const float* __restrict__ wgt,
                                                  bf16* __restrict__ lsumsT) {
    const int n = blockIdx.x, h = blockIdx.y;
    __shared__ float ks[CH_][65];
    __shared__ float vs[CH_][64];
    __shared__ float cw[CH_];
    const int tid = threadIdx.x;
    for (int e = tid; e < CH_ * 64; e += 256) {
        const int r = e >> 6, c = e & 63;
        const int t = n * CH_ + r;
        ks[r][c] = b2f(k0[(size_t)t * (NH_ * DK_) + h * DK_ + c]);
        vs[r][c] = b2f(v0[(size_t)t * (NH_ * DV_) + h * DV_ + c]);
    }
    if (tid < CH_) {
        const int t = n * CH_ + tid;
        cw[tid] = powf(DECAY_, (float)(CH_ - 1 - tid)) * wgt[t * NH_ + h];
    }
    __syncthreads();
    const int j = tid & 63, ig = tid >> 6;   // j = k-dim, rows = v-dim
    float acc[16] = {};
    for (int idx = 0; idx < CH_; idx++) {
        const float ck = cw[idx] * ks[idx][j];
        #pragma unroll
        for (int r = 0; r < 16; r++) acc[r] += vs[idx][ig * 16 + r] * ck;
    }
    bf16* outp = lsumsT + ((size_t)(n * NH_ + h)) * (DK_ * DV_);
    #pragma unroll
    for (int r = 0; r < 16; r++) outp[(ig * 16 + r) * 64 + j] = f2b(acc[r]);
}

// ---------------------------------------------------------------------------
// chunk_output, batch-merged + LDS-SLIMMED (mega-validated layout):
//  - FW combine carried in REGISTERS through phase A; FWT written overlaying
//    Ks after barrier2 (saves the 8KB FWT buffer).
//  - V^T stored sw64 (8KB) instead of stride-72 (9.2KB).
//  LDS: QsAm 32KB + Ks/FWT 8KB + VT 8KB + 0.5KB = 49.7KB -> 3 blocks/CU
//  (was 58.9KB -> 2 blocks/CU). Latency-bound kernel => +50% TLP.
// ---------------------------------------------------------------------------
__global__ __launch_bounds__(256, 3) void chunk_output(const bf16* __restrict__ q,
                                                    const bf16* __restrict__ k0,
                                                    const bf16* __restrict__ v0,
                                                    const float* __restrict__ wgt,
                                                    const bf16* __restrict__ lsumsT,
                                                    bf16* __restrict__ retr) {
    const int n = blockIdx.x, h = blockIdx.y;
    __shared__ bf16 QsAm[4][64 * 64];   // per-batch Q (sw64), then Am (sw64)
    __shared__ bf16 KsFWT[64 * 64];     // phase A: Ks (sw64); then FWT overlay
    __shared__ bf16 VT[64 * 64];        // sw64
    __shared__ float dpow[64], winv[64];
    const int tid = threadIdx.x, lane = tid & 63, w = tid >> 6;  // w = batch
    const int quad = lane >> 4, l16 = lane & 15;
    const int t0 = n * CH_;
    const int lrow = lane >> 3;
    const int lcol = ((lane & 7) ^ lrow) * 8;           // XOR-swizzled source col

    // stage own-batch Q tile (8 segs x 1KB) + cooperative K tile (2 segs/wave)
    #pragma unroll
    for (int seg = 0; seg < 8; seg++) {
        const int row = seg * 8 + lrow;
        gl2lds16(q + ((size_t)(w * S_ + t0 + row)) * 512 + h * 64 + lcol, &QsAm[w][seg * 512]);
    }
    #pragma unroll
    for (int c = 0; c < 2; c++) {
        const int seg = w * 2 + c;
        const int row = seg * 8 + lrow;
        gl2lds16(k0 + ((size_t)(t0 + row)) * 512 + h * 64 + lcol, &KsFWT[seg * 512]);
    }
    // FW combine -> REGISTERS (carried through phase A)
    float fwacc[16] = {};
    {
        const float dcp[4] = { 1.0f, 0.0375241f, 1.40806e-3f, 5.28365e-5f };
        #pragma unroll
        for (int jj = 1; jj <= 4; jj++) {
            const int nm = n - jj;
            if (nm < 0) break;
            const ushort* Lp = (const ushort*)(lsumsT + ((size_t)(nm * NH_ + h)) * 4096) + tid * 16;
            #pragma unroll
            for (int u = 0; u < 4; u++) {
                float f[4];
                cvt4(reinterpret_cast<const ushort4*>(Lp)[u], f);
                #pragma unroll
                for (int e = 0; e < 4; e++) fwacc[u * 4 + e] += dcp[jj - 1] * f[e];
            }
        }
    }
    // V^T staging, XOR-swizzled 64-stride
    {
        ushort4 vreg[4];
        const int jb = (tid & 15) * 4;   // 4 consecutive v-cols
        const int sb = tid >> 4;         // s = sb + 16*it
        #pragma unroll
        for (int it = 0; it < 4; it++)
            vreg[it] = *reinterpret_cast<const ushort4*>(
                v0 + ((size_t)(t0 + sb + it * 16)) * 512 + h * 64 + jb);
        ushort* VTu = reinterpret_cast<ushort*>(VT);
        #pragma unroll
        for (int it = 0; it < 4; it++) {
            const int s = sb + it * 16;
            #pragma unroll
            for (int c = 0; c < 4; c++) {
                const int v = jb + c;
                const ushort val = c == 0 ? vreg[it].x : c == 1 ? vreg[it].y
                                 : c == 2 ? vreg[it].z : vreg[it].w;
                VTu[v * 64 + (((s >> 3) ^ (v & 7)) << 3) + (s & 7)] = val;
            }
        }
    }
    if (tid < 64) {
        dpow[tid] = powf(DECAY_, (float)tid);
        winv[tid] = wgt[(t0 + tid) * NH_ + h] * powf(DECAY_, -(float)(tid + 1));
    }
    __syncthreads();   // sync1: gl2lds drained; VT/dpow/winv visible

    const int cb0 = ((quad) ^ (l16 & 7)) * 8;
    const int cb1 = ((4 + quad) ^ (l16 & 7)) * 8;
    bf16* Qw = &QsAm[w][0];

    // Q fragments for all 4 row-blocks (live through B1 in registers)
    bf16x8 af[4][2];
    #pragma unroll
    for (int mt = 0; mt < 4; mt++) {
        af[mt][0] = *reinterpret_cast<const bf16x8*>(&Qw[(mt * 16 + l16) * 64 + cb0]);
        af[mt][1] = *reinterpret_cast<const bf16x8*>(&Qw[(mt * 16 + l16) * 64 + cb1]);
    }

    // Phase A: S = Q @ K^T, full 64x64 per wave
    f32x4 acc[4][4] = {};
    #pragma unroll
    for (int kh = 0; kh < 2; kh++) {
        bf16x8 bk[4];
        #pragma unroll
        for (int nt = 0; nt < 4; nt++)
            bk[nt] = *reinterpret_cast<const bf16x8*>(
                &KsFWT[(nt * 16 + l16) * 64 + (kh ? cb1 : cb0)]);
        #pragma unroll
        for (int mt = 0; mt < 4; mt++)
            #pragma unroll
            for (int nt = 0; nt < 4; nt++)
                acc[mt][nt] = __builtin_amdgcn_mfma_f32_16x16x32_bf16(
                    af[mt][kh], bk[nt], acc[mt][nt], 0, 0, 0);
    }

    // mask + decay + gate -> Am (sw64) into own Q region (same-wave only)
    const float pmt[4] = { 1.0f, 0.4401266694f, 0.1937114891f, 0.0852578070f };
    const f32x4 dpb = *reinterpret_cast<const f32x4*>(&dpow[quad * 4]);
    float winv_l[4];
    #pragma unroll
    for (int nt = 0; nt < 4; nt++) winv_l[nt] = winv[nt * 16 + l16];
    #pragma unroll
    for (int mt = 0; mt < 4; mt++)
        #pragma unroll
        for (int nt = 0; nt < 4; nt++)
            #pragma unroll
            for (int r = 0; r < 4; r++) {
                const int tt = mt * 16 + quad * 4 + r;
                const int s = nt * 16 + l16;
                const float v = (s < tt) ? acc[mt][nt][r] * (dpb[r] * pmt[mt]) * winv_l[nt] : 0.f;
                Qw[tt * 64 + (((s >> 3) ^ (tt & 7)) << 3) + (s & 7)] = f2b(v);
            }
    __syncthreads();   // sync2: all waves finished reading Ks
    // FWT write (overlays Ks) from fwacc regs
    {
        const int frow = tid >> 2;                       // FWT row (v-dim)
        #pragma unroll
        for (int half = 0; half < 2; half++) {
            const int cb = (tid & 3) * 2 + half;         // logical colblock
            union { bf16 b8v[8]; bf16x8 v; } t;
            #pragma unroll
            for (int e = 0; e < 8; e++) t.b8v[e] = f2b(fwacc[half * 8 + e]);
            *reinterpret_cast<bf16x8*>(&KsFWT[frow * 64 + (cb ^ (frow & 7)) * 8]) = t.v;
        }
    }
    __syncthreads();   // sync3: FWT visible

    // Phase B1: O = Q @ FWT^T
    f32x4 o[4][4] = {};
    #pragma unroll
    for (int kh = 0; kh < 2; kh++) {
        bf16x8 ff[4];
        #pragma unroll
        for (int nt = 0; nt < 4; nt++)
            ff[nt] = *reinterpret_cast<const bf16x8*>(
                &KsFWT[(nt * 16 + l16) * 64 + (kh ? cb1 : cb0)]);
        #pragma unroll
        for (int mt = 0; mt < 4; mt++)
            #pragma unroll
            for (int nt = 0; nt < 4; nt++)
                o[mt][nt] = __builtin_amdgcn_mfma_f32_16x16x32_bf16(
                    af[mt][kh], ff[nt], o[mt][nt], 0, 0, 0);
    }
    #pragma unroll
    for (int mt = 0; mt < 4; mt++)
        #pragma unroll
        for (int nt = 0; nt < 4; nt++)
            #pragma unroll
            for (int r = 0; r < 4; r++) o[mt][nt][r] *= dpb[r] * pmt[mt];

    // Phase B2: O += Am @ VT^T  (Am read back from own region, in-wave order)
    #pragma unroll
    for (int kh = 0; kh < 2; kh++) {
        bf16x8 am[4], vf[4];
        #pragma unroll
        for (int mt = 0; mt < 4; mt++)
            am[mt] = *reinterpret_cast<const bf16x8*>(
                &Qw[(mt * 16 + l16) * 64 + (kh ? cb1 : cb0)]);
        #pragma unroll
        for (int nt = 0; nt < 4; nt++)
            vf[nt] = *reinterpret_cast<const bf16x8*>(
                &VT[(nt * 16 + l16) * 64 + (kh ? cb1 : cb0)]);
        #pragma unroll
        for (int mt = 0; mt < 4; mt++)
            #pragma unroll
            for (int nt = 0; nt < 4; nt++)
                o[mt][nt] = __builtin_amdgcn_mfma_f32_16x16x32_bf16(
                    am[mt], vf[nt], o[mt][nt], 0, 0, 0);
    }

    #pragma unroll
    for (int mt = 0; mt < 4; mt++)
        #pragma unroll
        for (int nt = 0; nt < 4; nt++)
            #pragma unroll
            for (int r = 0; r < 4; r++) {
                const int tt = mt * 16 + quad * 4 + r;
                retr[((size_t)(w * S_ + t0 + tt)) * 512 + h * 64 + nt * 16 + l16] =
                    f2b(o[mt][nt][r]);
            }
}

// ---------------------------------------------------------------------------
extern "C" void kernel_launch(void* const* d_in, const int* in_sizes, int n_in,
                              void* d_out, int out_size, void* d_ws, size_t ws_size,
                              hipStream_t stream) {
    const float* x  = (const float*)d_in[0];
    const float* wk = (const float*)d_in[1];
    const float* wv = (const float*)d_in[2];
    const float* wq = (const float*)d_in[3];
    const float* wg = (const float*)d_in[4];
    const float* wo = (const float*)d_in[5];
    float* out = (float*)d_out;

    const size_t MB1 = 1ull << 20;
    char* w = (char*)d_ws;
    bf16*  qbuf    = (bf16*)(w);                          // 16 MB
    bf16*  k0buf   = (bf16*)(w + 16 * MB1);               // 4 MB
    bf16*  v0buf   = (bf16*)(w + 20 * MB1);               // 4 MB
    float* wgt     = (float*)(w + 24 * MB1);              // 128 KB
    bf16*  wqb     = (bf16*)(w + 24 * MB1 + (128ull<<10));
    bf16*  wkb     = (bf16*)(w + 24 * MB1 + (128ull<<10) + 1*786432);
    bf16*  wvb     = (bf16*)(w + 24 * MB1 + (128ull<<10) + 2*786432);
    bf16*  wob     = (bf16*)(w + 24 * MB1 + (128ull<<10) + 3*786432);
    bf16*  lsumsT  = (bf16*)(w + 28 * MB1);               // 4 MB
    bf16*  retr    = (bf16*)(w + 32 * MB1);               // 16 MB
    bf16*  xb      = (bf16*)(w + 48 * MB1);               // 24 MB

    const int MB = B_ * S_;  // 16384

    // fused casts + gate (1 dispatch)
    cast_fused<<<MB + 2048, 192, 0, stream>>>(x, xb, wg, wgt,
                                              wq, wk, wv, wo, wqb, wkb, wvb, wob);

    // fused q/k/v projections (1 dispatch, XCD-strip-mapped)
    proj_fused<<<768, 256, 0, stream>>>(xb, wqb, wkb, wvb, qbuf, k0buf, v0buf);

    // chunked scan (state combine fused into chunk_output, batch-merged)
    chunk_sums<<<dim3(NCH_, NH_), 256, 0, stream>>>(k0buf, v0buf, wgt, lsumsT);
    chunk_output<<<dim3(NCH_, NH_), 256, 0, stream>>>(qbuf, k0buf, v0buf, wgt, lsumsT, retr);

    // out = x + retrieved @ w_out^T
    gemm_out<<<dim3(D_ / 128, MB / 128), 256, 0, stream>>>(retr, wob, x, out);
}

// Round 8
// 179.789 us; speedup vs baseline: 1.1237x; 1.0286x over previous
//
#include <hip/hip_runtime.h>
#include <hip/hip_bf16.h>

typedef __hip_bfloat16 bf16;
typedef __attribute__((ext_vector_type(8))) short   bf16x8;  // 8 bf16 = 4 VGPRs
typedef __attribute__((ext_vector_type(4))) float   f32x4;

#define B_   4
#define S_   4096
#define D_   768
#define NH_  8
#define DK_  64
#define DV_  64
#define CH_  64              // chunk length
#define NCH_ (S_/CH_)        // 64 chunks
#define DECAY_ 0.95f
#define WSTR_  0.1f
#define L2D_  (-0.07400058144f)   // log2(0.95)

__device__ __forceinline__ float b2f(bf16 v) { return __bfloat162float(v); }
__device__ __forceinline__ bf16  f2b(float v) { return __float2bfloat16(v); }

// async global -> LDS, 16 bytes per lane; lds base must be wave-uniform,
// HW writes lane i at lds + i*16.
__device__ __forceinline__ void gl2lds16(const bf16* g, bf16* lds) {
    __builtin_amdgcn_global_load_lds(
        (const __attribute__((address_space(1))) void*)g,
        (__attribute__((address_space(3))) void*)lds, 16, 0, 0);
}

__device__ __forceinline__ void cvt4(ushort4 u, float f[4]) {
    union { unsigned u; float f; } c;
    c.u = (unsigned)u.x << 16; f[0] = c.f;
    c.u = (unsigned)u.y << 16; f[1] = c.f;
    c.u = (unsigned)u.z << 16; f[2] = c.f;
    c.u = (unsigned)u.w << 16; f[3] = c.f;
}

// ---------------------------------------------------------------------------
// Fused cast kernel, 192 threads (R4 proven):
//  blocks [0, 16384): x row cast fp32->bf16; rows < 4096 also compute gate.
//  blocks [16384, 18432): the four 512x768 weight matrices cast (512 blk each).
// ---------------------------------------------------------------------------
__global__ __launch_bounds__(192) void cast_fused(const float* __restrict__ x,
                                                  bf16* __restrict__ xb,
                                                  const float* __restrict__ wg,
                                                  float* __restrict__ wgt,
                                                  const float* __restrict__ wq,
                                                  const float* __restrict__ wk,
                                                  const float* __restrict__ wv,
                                                  const float* __restrict__ wo,
                                                  bf16* __restrict__ dq, bf16* __restrict__ dk,
                                                  bf16* __restrict__ dv, bf16* __restrict__ dob) {
    const int tid = threadIdx.x;
    if (blockIdx.x >= (B_ * S_)) {
        const int idx = blockIdx.x - B_ * S_;          // 0..2047
        const int which = idx >> 9, b = idx & 511;     // 512 blocks per matrix
        const float* src = which == 0 ? wq : which == 1 ? wk : which == 2 ? wv : wo;
        bf16*       dst = which == 0 ? dq : which == 1 ? dk : which == 2 ? dv : dob;
        const int i = (b * 192 + tid) * 4;
        const float4 v = *reinterpret_cast<const float4*>(src + i);
        union { bf16 b4[4]; ushort4 u; } t;
        t.b4[0] = f2b(v.x); t.b4[1] = f2b(v.y); t.b4[2] = f2b(v.z); t.b4[3] = f2b(v.w);
        *reinterpret_cast<ushort4*>(dst + i) = t.u;
        return;
    }
    const int s = blockIdx.x;
    const float4 v = *reinterpret_cast<const float4*>(x + (size_t)s * D_ + tid * 4);
    union { bf16 b4[4]; ushort4 u; } t;
    t.b4[0] = f2b(v.x); t.b4[1] = f2b(v.y); t.b4[2] = f2b(v.z); t.b4[3] = f2b(v.w);
    *reinterpret_cast<ushort4*>(xb + (size_t)s * D_ + tid * 4) = t.u;

    if (s < S_) {   // batch 0 only
        __shared__ float red[3 * 8];
        float p[8];
        const float* wgp = wg + tid * 4;
        #pragma unroll
        for (int h = 0; h < 8; h++) {
            const float4 wv4 = *reinterpret_cast<const float4*>(wgp + h * D_);
            p[h] = v.x * wv4.x + v.y * wv4.y + v.z * wv4.z + v.w * wv4.w;
        }
        #pragma unroll
        for (int h = 0; h < 8; h++)
            #pragma unroll
            for (int off = 32; off; off >>= 1) p[h] += __shfl_down(p[h], off);
        const int w = tid >> 6, lane = tid & 63;
        if (lane == 0) {
            #pragma unroll
            for (int h = 0; h < 8; h++) red[w * 8 + h] = p[h];
        }
        __syncthreads();
        if (tid < 8) {
            const float sum = red[tid] + red[8 + tid] + red[16 + tid];
            wgt[s * NH_ + tid] = WSTR_ / (1.f + expf(-sum));
        }
    }
}

// ---------------------------------------------------------------------------
// Shared MFMA GEMM body v4 (R4 proven): A-dbuf gl2lds (32KB) + B single (16KB)
// = 48KB -> 3 blocks/CU. PIN (R3/R6): all staging must be global_load_lds;
// register round-trips lose even with full-iteration wait windows.
// NEW (R8): for ADDX, the 64 X values are prefetched into registers at the
// top of the LAST K-iteration so their latency hides under the final MFMA
// cluster instead of serializing the epilogue. +64 VGPR (152 <= 168 cap;
// occupancy is LDS-bound at 3 blocks/CU, unchanged).
// ---------------------------------------------------------------------------
template<typename TC, int ADDX, int NITER>
__device__ __forceinline__ void gemm_body(bf16* As, bf16* Bs,
                                          const bf16* __restrict__ A,
                                          const bf16* __restrict__ Bm,
                                          const float* __restrict__ X,
                                          TC* __restrict__ C,
                                          int bm, int bn, int K, int N) {
    const int tid = threadIdx.x, lane = tid & 63, w = tid >> 6;
    const int quad = lane >> 4, l16 = lane & 15;
    const int wm = (w >> 1) * 64, wn = (w & 1) * 64;
    const int lrow = lane >> 3;                         // 0..7 within segment
    const int lcol = ((lane & 7) ^ lrow) * 8;           // XOR-swizzled source col

    f32x4 acc[4][4] = {};
    float xv[4][4][4];                                  // X prefetch (ADDX only)

    auto STAGE_A = [&](int it, int buf) {
        const int k0 = it * 64;
        bf16* Ad = As + buf * 8192;
        #pragma unroll
        for (int c = 0; c < 4; c++) {
            const int seg = w * 4 + c;                  // 0..15, 8 rows each
            const int row = seg * 8 + lrow;
            gl2lds16(A + (size_t)(bm + row) * K + k0 + lcol, &Ad[seg * 512]);
        }
    };
    auto STAGE_B = [&](int it) {
        const int k0 = it * 64;
        #pragma unroll
        for (int c = 0; c < 4; c++) {
            const int seg = w * 4 + c;
            const int row = seg * 8 + lrow;
            gl2lds16(Bm + (size_t)(bn + row) * K + k0 + lcol, &Bs[seg * 512]);
        }
    };

    STAGE_A(0, 0);          // oldest in queue
    STAGE_B(0);

    for (int it = 0; it < NITER; ++it) {
        const int cur = it & 1;
        if (it + 1 < NITER) {
            STAGE_A(it + 1, cur ^ 1);                   // full-iter window
            asm volatile("s_waitcnt vmcnt(4)" ::: "memory");  // A(it)+B(it) in
        } else {
            asm volatile("s_waitcnt vmcnt(0)" ::: "memory");
        }
        __builtin_amdgcn_s_barrier();                   // barrier1: tiles visible
        asm volatile("" ::: "memory");

        const bf16* Ar = As + cur * 8192;
        bf16x8 af[2][4], bfr[2][4];
        #pragma unroll
        for (int kh = 0; kh < 2; kh++)
            #pragma unroll
            for (int t = 0; t < 4; t++) {
                const int cb = ((kh * 4 + quad) ^ (l16 & 7)) * 8;
                af[kh][t]  = *reinterpret_cast<const bf16x8*>(&Ar[(wm + t * 16 + l16) * 64 + cb]);
                bfr[kh][t] = *reinterpret_cast<const bf16x8*>(&Bs[(wn + t * 16 + l16) * 64 + cb]);
            }
        asm volatile("s_waitcnt lgkmcnt(0)" ::: "memory");    // frags in regs
        __builtin_amdgcn_s_barrier();                   // barrier2: LDS free
        if (it + 1 < NITER) STAGE_B(it + 1);            // latency hides in MFMAs

        if (ADDX && it == NITER - 1) {
            // issue X loads now; latency hides under the final MFMA cluster
            #pragma unroll
            for (int mt = 0; mt < 4; mt++)
                #pragma unroll
                for (int nt = 0; nt < 4; nt++)
                    #pragma unroll
                    for (int r = 0; r < 4; r++)
                        xv[mt][nt][r] = X[(size_t)(bm + wm + mt * 16 + quad * 4 + r) * N
                                          + (bn + wn + nt * 16 + l16)];
        }

        #pragma unroll
        for (int kh = 0; kh < 2; kh++)
            #pragma unroll
            for (int mt = 0; mt < 4; mt++)
                #pragma unroll
                for (int nt = 0; nt < 4; nt++)
                    acc[mt][nt] = __builtin_amdgcn_mfma_f32_16x16x32_bf16(
                        af[kh][mt], bfr[kh][nt], acc[mt][nt], 0, 0, 0);
    }

    #pragma unroll
    for (int mt = 0; mt < 4; mt++)
        #pragma unroll
        for (int nt = 0; nt < 4; nt++)
            #pragma unroll
            for (int r = 0; r < 4; r++) {
                const int m = bm + wm + mt * 16 + quad * 4 + r;
                const int n = bn + wn + nt * 16 + l16;
                float v = acc[mt][nt][r];
                if (ADDX) v += xv[mt][nt][r];
                if (sizeof(TC) == 2) *(bf16*)&C[(size_t)m * N + n] = f2b(v);
                else                 *(float*)&C[(size_t)m * N + n] = v;
            }
}

// ---------------------------------------------------------------------------
// Fused q/k/v projection: 768 blocks, K=768, N=512 for all.
// ---------------------------------------------------------------------------
__global__ __launch_bounds__(256, 3) void proj_fused(const bf16* __restrict__ xb,
                                                  const bf16* __restrict__ wqb,
                                                  const bf16* __restrict__ wkb,
                                                  const bf16* __restrict__ wvb,
                                                  bf16* __restrict__ qbuf,
                                                  bf16* __restrict__ k0buf,
                                                  bf16* __restrict__ v0buf) {
    __shared__ bf16 As[2 * 128 * 64];   // A double-buffer (32KB)
    __shared__ bf16 Bs[128 * 64];       // B single (16KB) -> 48KB, 3 blocks/CU
    const int id = blockIdx.x;
    const int xcd = id & 7;
    int j = id >> 3;                                    // 0..95
    const bf16* Bm; bf16* C; int bm, bn;
    if (j < 64) {
        bm = (xcd + ((j >> 2) << 3)) * 128;             // q strip
        bn = (j & 3) * 128;
        Bm = wqb; C = qbuf;
    } else {
        j -= 64;
        bm = (xcd + ((j >> 3) << 3)) * 128;             // kv strip (rows < 4096)
        const int b8 = j & 7;
        bn = (b8 & 3) * 128;
        Bm = (b8 < 4) ? wkb : wvb;
        C  = (b8 < 4) ? k0buf : v0buf;
    }
    gemm_body<bf16, 0, 12>(As, Bs, xb, Bm, nullptr, C, bm, bn, D_, 512);
}

// ---------------------------------------------------------------------------
// Out-projection: out = x + retr @ wo^T.  grid (6,128), K=512, N=768.
// ---------------------------------------------------------------------------
__global__ __launch_bounds__(256, 3) void gemm_out(const bf16* __restrict__ retr,
                                                const bf16* __restrict__ wob,
                                                const float* __restrict__ x,
                                                float* __restrict__ out) {
    __shared__ bf16 As[2 * 128 * 64];
    __shared__ bf16 Bs[128 * 64];
    // XCD swizzle: blocks sharing an A-strip (by) land on one XCD.
    const int gx = gridDim.x, gy = gridDim.y;
    const int L = blockIdx.y * gx + blockIdx.x;
    const int rpx = gy >> 3;
    const int xcd = L & 7;
    const int i   = L >> 3;
    const int by = xcd * rpx + i / gx;
    const int bx = i % gx;
    gemm_body<float, 1, 8>(As, Bs, retr, wob, x, out, by * 128, bx * 128, 512, D_);
}

// ---------------------------------------------------------------------------
// lsumsT[n,h][v*64+k] = sum_{i<CH} 0.95^(CH-1-i) * w_i * v_i[v] * k_i[k]
// R8: ushort4-vectorized k/v staging (was scalar bf16 loads, 32/thread —
// Common-mistake #2); stride-68 float rows keep float4 stores 16B-aligned
// and LDS reads conflict-free. Pattern verified correct inside R5's mega.
// ---------------------------------------------------------------------------
__global__ __launch_bounds__(256) void chunk_sums(const bf16* __restrict__ k0,
                                                  const bf16* __restrict__ v0,
                                                  const float* __restrict__ wgt,
                                                  bf16* __restrict__ lsumsT) {
    const int n = blockIdx.x, h = blockIdx.y;
    __shared__ float ks[CH_ * 68];
    __shared__ float vs[CH_ * 68];
    __shared__ float cw[CH_];
    const int tid = threadIdx.x;
    const int r = tid >> 2, c0 = (tid & 3) * 16;
    {
        const ushort* kp = (const ushort*)k0 + ((size_t)(n * CH_ + r)) * 512 + h * 64 + c0;
        const ushort* vp = (const ushort*)v0 + ((size_t)(n * CH_ + r)) * 512 + h * 64 + c0;
        #pragma unroll
        for (int e = 0; e < 4; e++) {
            float fk[4], fv[4];
            cvt4(reinterpret_cast<const ushort4*>(kp)[e], fk);
            cvt4(reinterpret_cast<const ushort4*>(vp)[e], fv);
            union { float f[4]; float4 v4; } tk, tv;
            tk.f[0] = fk[0]; tk.f[1] = fk[1]; tk.f[2] = fk[2]; tk.f[3] = fk[3];
            tv.f[0] = fv[0]; tv.f[1] = fv[1]; tv.f[2] = fv[2]; tv.f[3] = fv[3];
            *reinterpret_cast<float4*>(&ks[r * 68 + c0 + e * 4]) = tk.v4;
            *reinterpret_cast<float4*>(&vs[r * 68 + c0 + e * 4]) = tv.v4;
        }
    }
    if (tid < CH_)
        cw[tid] = exp2f((float)(CH_ - 1 - tid) * L2D_) * wgt[(n * CH_ + tid) * NH_ + h];
    __syncthreads();
    const int j = tid & 63, ig = tid >> 6;   // j = k-dim, rows = v-dim
    float acc[16] = {};
    for (int idx = 0; idx < CH_; idx++) {
        const float ck = cw[idx] * ks[idx * 68 + j];
        #pragma unroll
        for (int rr = 0; rr < 16; rr++) acc[rr] += vs[idx * 68 + ig * 16 + rr] * ck;
    }
    bf16* outp = lsumsT + ((size_t)(n * NH_ + h)) * (DK_ * DV_);
    #pragma unroll
    for (int rr = 0; rr < 16; rr++) outp[(ig * 16 + rr) * 64 + j] = f2b(acc[rr]);
}

// ---------------------------------------------------------------------------
// chunk_output, batch-merged + LDS-slimmed (R7 proven, 3 blocks/CU);
// powf -> exp2f.
// ---------------------------------------------------------------------------
__global__ __launch_bounds__(256, 3) void chunk_output(const bf16* __restrict__ q,
                                                    const bf16* __restrict__ k0,
                                                    const bf16* __restrict__ v0,
                                                    const float* __restrict__ wgt,
                                                    const bf16* __restrict__ lsumsT,
                                                    bf16* __restrict__ retr) {
    const int n = blockIdx.x, h = blockIdx.y;
    __shared__ bf16 QsAm[4][64 * 64];   // per-batch Q (sw64), then Am (sw64)
    __shared__ bf16 KsFWT[64 * 64];     // phase A: Ks (sw64); then FWT overlay
    __shared__ bf16 VT[64 * 64];        // sw64
    __shared__ float dpow[64], winv[64];
    const int tid = threadIdx.x, lane = tid & 63, w = tid >> 6;  // w = batch
    const int quad = lane >> 4, l16 = lane & 15;
    const int t0 = n * CH_;
    const int lrow = lane >> 3;
    const int lcol = ((lane & 7) ^ lrow) * 8;           // XOR-swizzled source col

    // stage own-batch Q tile (8 segs x 1KB) + cooperative K tile (2 segs/wave)
    #pragma unroll
    for (int seg = 0; seg < 8; seg++) {
        const int row = seg * 8 + lrow;
        gl2lds16(q + ((size_t)(w * S_ + t0 + row)) * 512 + h * 64 + lcol, &QsAm[w][seg * 512]);
    }
    #pragma unroll
    for (int c = 0; c < 2; c++) {
        const int seg = w * 2 + c;
        const int row = seg * 8 + lrow;
        gl2lds16(k0 + ((size_t)(t0 + row)) * 512 + h * 64 + lcol, &KsFWT[seg * 512]);
    }
    // FW combine -> REGISTERS (carried through phase A)
    float fwacc[16] = {};
    {
        const float dcp[4] = { 1.0f, 0.0375241f, 1.40806e-3f, 5.28365e-5f };
        #pragma unroll
        for (int jj = 1; jj <= 4; jj++) {
            const int nm = n - jj;
            if (nm < 0) break;
            const ushort* Lp = (const ushort*)(lsumsT + ((size_t)(nm * NH_ + h)) * 4096) + tid * 16;
            #pragma unroll
            for (int u = 0; u < 4; u++) {
                float f[4];
                cvt4(reinterpret_cast<const ushort4*>(Lp)[u], f);
                #pragma unroll
                for (int e = 0; e < 4; e++) fwacc[u * 4 + e] += dcp[jj - 1] * f[e];
            }
        }
    }
    // V^T staging, XOR-swizzled 64-stride
    {
        ushort4 vreg[4];
        const int jb = (tid & 15) * 4;   // 4 consecutive v-cols
        const int sb = tid >> 4;         // s = sb + 16*it
        #pragma unroll
        for (int it = 0; it < 4; it++)
            vreg[it] = *reinterpret_cast<const ushort4*>(
                v0 + ((size_t)(t0 + sb + it * 16)) * 512 + h * 64 + jb);
        ushort* VTu = reinterpret_cast<ushort*>(VT);
        #pragma unroll
        for (int it = 0; it < 4; it++) {
            const int s = sb + it * 16;
            #pragma unroll
            for (int c = 0; c < 4; c++) {
                const int v = jb + c;
                const ushort val = c == 0 ? vreg[it].x : c == 1 ? vreg[it].y
                                 : c == 2 ? vreg[it].z : vreg[it].w;
                VTu[v * 64 + (((s >> 3) ^ (v & 7)) << 3) + (s & 7)] = val;
            }
        }
    }
    if (tid < 64) {
        dpow[tid] = exp2f((float)tid * L2D_);
        winv[tid] = wgt[(t0 + tid) * NH_ + h] * exp2f(-(float)(tid + 1) * L2D_);
    }
    __syncthreads();   // sync1: gl2lds drained; VT/dpow/winv visible

    const int cb0 = ((quad) ^ (l16 & 7)) * 8;
    const int cb1 = ((4 + quad) ^ (l16 & 7)) * 8;
    bf16* Qw = &QsAm[w][0];

    // Q fragments for all 4 row-blocks (live through B1 in registers)
    bf16x8 af[4][2];
    #pragma unroll
    for (int mt = 0; mt < 4; mt++) {
        af[mt][0] = *reinterpret_cast<const bf16x8*>(&Qw[(mt * 16 + l16) * 64 + cb0]);
        af[mt][1] = *reinterpret_cast<const bf16x8*>(&Qw[(mt * 16 + l16) * 64 + cb1]);
    }

    // Phase A: S = Q @ K^T, full 64x64 per wave
    f32x4 acc[4][4] = {};
    #pragma unroll
    for (int kh = 0; kh < 2; kh++) {
        bf16x8 bk[4];
        #pragma unroll
        for (int nt = 0; nt < 4; nt++)
            bk[nt] = *reinterpret_cast<const bf16x8*>(
                &KsFWT[(nt * 16 + l16) * 64 + (kh ? cb1 : cb0)]);
        #pragma unroll
        for (int mt = 0; mt < 4; mt++)
            #pragma unroll
            for (int nt = 0; nt < 4; nt++)
                acc[mt][nt] = __builtin_amdgcn_mfma_f32_16x16x32_bf16(
                    af[mt][kh], bk[nt], acc[mt][nt], 0, 0, 0);
    }

    // mask + decay + gate -> Am (sw64) into own Q region (same-wave only)
    const float pmt[4] = { 1.0f, 0.4401266694f, 0.1937114891f, 0.0852578070f };
    const f32x4 dpb = *reinterpret_cast<const f32x4*>(&dpow[quad * 4]);
    float winv_l[4];
    #pragma unroll
    for (int nt = 0; nt < 4; nt++) winv_l[nt] = winv[nt * 16 + l16];
    #pragma unroll
    for (int mt = 0; mt < 4; mt++)
        #pragma unroll
        for (int nt = 0; nt < 4; nt++)
            #pragma unroll
            for (int r = 0; r < 4; r++) {
                const int tt = mt * 16 + quad * 4 + r;
                const int s = nt * 16 + l16;
                const float v = (s < tt) ? acc[mt][nt][r] * (dpb[r] * pmt[mt]) * winv_l[nt] : 0.f;
                Qw[tt * 64 + (((s >> 3) ^ (tt & 7)) << 3) + (s & 7)] = f2b(v);
            }
    __syncthreads();   // sync2: all waves finished reading Ks
    // FWT write (overlays Ks) from fwacc regs
    {
        const int frow = tid >> 2;                       // FWT row (v-dim)
        #pragma unroll
        for (int half = 0; half < 2; half++) {
            const int cb = (tid & 3) * 2 + half;         // logical colblock
            union { bf16 b8v[8]; bf16x8 v; } t;
            #pragma unroll
            for (int e = 0; e < 8; e++) t.b8v[e] = f2b(fwacc[half * 8 + e]);
            *reinterpret_cast<bf16x8*>(&KsFWT[frow * 64 + (cb ^ (frow & 7)) * 8]) = t.v;
        }
    }
    __syncthreads();   // sync3: FWT visible

    // Phase B1: O = Q @ FWT^T
    f32x4 o[4][4] = {};
    #pragma unroll
    for (int kh = 0; kh < 2; kh++) {
        bf16x8 ff[4];
        #pragma unroll
        for (int nt = 0; nt < 4; nt++)
            ff[nt] = *reinterpret_cast<const bf16x8*>(
                &KsFWT[(nt * 16 + l16) * 64 + (kh ? cb1 : cb0)]);
        #pragma unroll
        for (int mt = 0; mt < 4; mt++)
            #pragma unroll
            for (int nt = 0; nt < 4; nt++)
                o[mt][nt] = __builtin_amdgcn_mfma_f32_16x16x32_bf16(
                    af[mt][kh], ff[nt], o[mt][nt], 0, 0, 0);
    }
    #pragma unroll
    for (int mt = 0; mt < 4; mt++)
        #pragma unroll
        for (int nt = 0; nt < 4; nt++)
            #pragma unroll
            for (int r = 0; r < 4; r++) o[mt][nt][r] *= dpb[r] * pmt[mt];

    // Phase B2: O += Am @ VT^T  (Am read back from own region, in-wave order)
    #pragma unroll
    for (int kh = 0; kh < 2; kh++) {
        bf16x8 am[4], vf[4];
        #pragma unroll
        for (int mt = 0; mt < 4; mt++)
            am[mt] = *reinterpret_cast<const bf16x8*>(
                &Qw[(mt * 16 + l16) * 64 + (kh ? cb1 : cb0)]);
        #pragma unroll
        for (int nt = 0; nt < 4; nt++)
            vf[nt] = *reinterpret_cast<const bf16x8*>(
                &VT[(nt * 16 + l16) * 64 + (kh ? cb1 : cb0)]);
        #pragma unroll
        for (int mt = 0; mt < 4; mt++)
            #pragma unroll
            for (int nt = 0; nt < 4; nt++)
                o[mt][nt] = __builtin_amdgcn_mfma_f32_16x16x32_bf16(
                    am[mt], vf[nt], o[mt][nt], 0, 0, 0);
    }

    #pragma unroll
    for (int mt = 0; mt < 4; mt++)
        #pragma unroll
        for (int nt = 0; nt < 4; nt++)
            #pragma unroll
            for (int r = 0; r < 4; r++) {
                const int tt = mt * 16 + quad * 4 + r;
                retr[((size_t)(w * S_ + t0 + tt)) * 512 + h * 64 + nt * 16 + l16] =
                    f2b(o[mt][nt][r]);
            }
}

// ---------------------------------------------------------------------------
extern "C" void kernel_launch(void* const* d_in, const int* in_sizes, int n_in,
                              void* d_out, int out_size, void* d_ws, size_t ws_size,
                              hipStream_t stream) {
    const float* x  = (const float*)d_in[0];
    const float* wk = (const float*)d_in[1];
    const float* wv = (const float*)d_in[2];
    const float* wq = (const float*)d_in[3];
    const float* wg = (const float*)d_in[4];
    const float* wo = (const float*)d_in[5];
    float* out = (float*)d_out;

    const size_t MB1 = 1ull << 20;
    char* w = (char*)d_ws;
    bf16*  qbuf    = (bf16*)(w);                          // 16 MB
    bf16*  k0buf   = (bf16*)(w + 16 * MB1);               // 4 MB
    bf16*  v0buf   = (bf16*)(w + 20 * MB1);               // 4 MB
    float* wgt     = (float*)(w + 24 * MB1);              // 128 KB
    bf16*  wqb     = (bf16*)(w + 24 * MB1 + (128ull<<10));
    bf16*  wkb     = (bf16*)(w + 24 * MB1 + (128ull<<10) + 1*786432);
    bf16*  wvb     = (bf16*)(w + 24 * MB1 + (128ull<<10) + 2*786432);
    bf16*  wob     = (bf16*)(w + 24 * MB1 + (128ull<<10) + 3*786432);
    bf16*  lsumsT  = (bf16*)(w + 28 * MB1);               // 4 MB
    bf16*  retr    = (bf16*)(w + 32 * MB1);               // 16 MB
    bf16*  xb      = (bf16*)(w + 48 * MB1);               // 24 MB

    const int MB = B_ * S_;  // 16384

    // fused casts + gate (1 dispatch)
    cast_fused<<<MB + 2048, 192, 0, stream>>>(x, xb, wg, wgt,
                                              wq, wk, wv, wo, wqb, wkb, wvb, wob);

    // fused q/k/v projections (1 dispatch, XCD-strip-mapped)
    proj_fused<<<768, 256, 0, stream>>>(xb, wqb, wkb, wvb, qbuf, k0buf, v0buf);

    // chunked scan (state combine fused into chunk_output, batch-merged)
    chunk_sums<<<dim3(NCH_, NH_), 256, 0, stream>>>(k0buf, v0buf, wgt, lsumsT);
    chunk_output<<<dim3(NCH_, NH_), 256, 0, stream>>>(qbuf, k0buf, v0buf, wgt, lsumsT, retr);

    // out = x + retrieved @ w_out^T
    gemm_out<<<dim3(D_ / 128, MB / 128), 256, 0, stream>>>(retr, wob, x, out);
}